// Round 1
// baseline (157.666 us; speedup 1.0000x reference)
//
#include <hip/hip_runtime.h>
#include <hip/hip_bf16.h>

#define B_   16
#define NT_  4096
#define D_   512
#define CHUNK 256

// ---------------------------------------------------------------------------
// Kernel 1: stable compaction of valid tokens per batch row + meta.
// grid = B_*16 blocks (one per (row, 256-chunk)), 256 threads.
// Robust to any validity pattern (doesn't assume prefix validity).
// ---------------------------------------------------------------------------
__global__ __launch_bounds__(256) void compact_kernel(const int* __restrict__ text,
                                                      int* __restrict__ tok,
                                                      int* __restrict__ meta) {
    const int b = blockIdx.x >> 4;   // 16 chunks per row
    const int c = blockIdx.x & 15;
    const int t = threadIdx.x;
    const int lane = t & 63;
    const int wid  = t >> 6;
    const int* row = text + b * NT_;

    // 1) count valid elements in preceding region [0, c*CHUNK)
    int pre = 0;
    for (int i = t; i < c * CHUNK; i += 256) pre += (row[i] >= 0) ? 1 : 0;
    #pragma unroll
    for (int off = 32; off > 0; off >>= 1) pre += __shfl_down(pre, off, 64);
    __shared__ int s_pre[4];
    if (lane == 0) s_pre[wid] = pre;
    __syncthreads();
    const int chunk_base = s_pre[0] + s_pre[1] + s_pre[2] + s_pre[3];

    // 2) own element: wave inclusive scan of predicate
    const int v = row[c * CHUNK + t];
    const int pred = (v >= 0) ? 1 : 0;
    int x = pred;
    #pragma unroll
    for (int off = 1; off < 64; off <<= 1) {
        int y = __shfl_up(x, off, 64);
        if (lane >= off) x += y;
    }
    __shared__ int s_wsum[4];
    if (lane == 63) s_wsum[wid] = x;
    __syncthreads();
    int woff = 0;
    for (int w = 0; w < wid; ++w) woff += s_wsum[w];

    if (pred) tok[b * NT_ + chunk_base + woff + (x - pred)] = v + 1;

    // 3) last chunk's last thread has the row total -> meta
    if (c == 15 && t == 255) {
        const int L  = chunk_base + woff + x;
        const int Ls = (L > 0) ? L : 1;
        const int base = NT_ / Ls;
        const int rem  = NT_ % Ls;
        meta[b * 4 + 0] = L;
        meta[b * 4 + 1] = base;
        meta[b * 4 + 2] = rem;
        meta[b * 4 + 3] = (Ls - rem) * base;   // boundary
    }
}

// ---------------------------------------------------------------------------
// Kernel 2: per-(b,p) token id (does the integer divisions once per position).
// grid = B_*NT_/256 = 256 blocks, 256 threads. token = -1 => write zeros.
// ---------------------------------------------------------------------------
__global__ __launch_bounds__(256) void map_kernel(const int* __restrict__ tok,
                                                  const int* __restrict__ meta,
                                                  int* __restrict__ exp_tok) {
    const int pidx = blockIdx.x * 256 + threadIdx.x;  // [0, B_*NT_)
    const int b = pidx >> 12;
    const int p = pidx & (NT_ - 1);
    const int L = meta[b * 4 + 0];
    int token = -1;
    if (L > 0) {
        const int base     = meta[b * 4 + 1];
        const int rem      = meta[b * 4 + 2];
        const int boundary = meta[b * 4 + 3];
        const int j = (p < boundary) ? (p / base)
                                     : ((L - rem) + (p - boundary) / (base + 1));
        token = tok[b * NT_ + j];
    }
    exp_tok[pidx] = token;
}

// ---------------------------------------------------------------------------
// Kernel 3: expand — one float4 emb load + one coalesced float4 store / thread.
// grid = B_*NT_*D_/4/256 = 32768 blocks, 256 threads.
// ---------------------------------------------------------------------------
__global__ __launch_bounds__(256) void expand_kernel(const float4* __restrict__ emb,
                                                     const int* __restrict__ exp_tok,
                                                     float4* __restrict__ out) {
    const int tid  = blockIdx.x * 256 + threadIdx.x;  // float4 index
    const int pidx = tid >> 7;                        // D_/4 = 128 float4 per row
    const int d4   = tid & 127;
    const int tkn  = exp_tok[pidx];
    float4 v;
    if (tkn < 0) {
        v = make_float4(0.f, 0.f, 0.f, 0.f);
    } else {
        v = emb[(size_t)tkn * (D_ / 4) + d4];
    }
    out[tid] = v;
}

extern "C" void kernel_launch(void* const* d_in, const int* in_sizes, int n_in,
                              void* d_out, int out_size, void* d_ws, size_t ws_size,
                              hipStream_t stream) {
    const int*   text = (const int*)d_in[0];     // (B, NT) int
    // d_in[1] = seq_len scalar (== 4096, compile-time constant here)
    const float* emb  = (const float*)d_in[2];   // (V+1, D) f32
    float*       out  = (float*)d_out;           // (B, NT, D) f32

    int* tok     = (int*)d_ws;                   // B_*NT_ ints
    int* meta    = tok + B_ * NT_;               // B_*4 ints
    int* exp_tok = meta + B_ * 4;                // B_*NT_ ints

    compact_kernel<<<B_ * 16, 256, 0, stream>>>(text, tok, meta);
    map_kernel<<<(B_ * NT_) / 256, 256, 0, stream>>>(tok, meta, exp_tok);
    expand_kernel<<<(B_ * NT_ * (D_ / 4)) / 256, 256, 0, stream>>>(
        (const float4*)emb, exp_tok, (float4*)out);
}